// Round 2
// baseline (2092.554 us; speedup 1.0000x reference)
//
#include <hip/hip_runtime.h>
#include <hip/hip_bf16.h>

// ---------------- problem constants ----------------
static constexpr int kNE  = 200000;   // emails
static constexpr int kNU  = 100000;   // users
static constexpr int kE   = 1000000;  // edges per type

// ---------------- workspace layout (4-byte element offsets) ----------------
// Liveness: B0=xe (dead after u1-lin) -> reused for mean_ue2/e2; B1=mean_ue1/e1 -> reused for h;
// B2=mean_eu/u1. Total ~268 MB.
static constexpr long long O_FLAG = 0;                     // int flag (64 reserved)
static constexpr long long SZ_NEH = (long long)kNE * 128;  // 25.6M
static constexpr long long SZ_NUH = (long long)kNU * 128;  // 12.8M
static constexpr long long O_B0   = 64;
static constexpr long long O_B1   = O_B0 + SZ_NEH;
static constexpr long long O_B2   = O_B1 + SZ_NEH;
static constexpr long long O_W    = O_B2 + SZ_NUH;
static constexpr long long O_WEM  = O_W;                   // 8192
static constexpr long long O_BEM  = O_WEM + 8192;          // 128
static constexpr long long O_W1N  = O_BEM + 128;           // 16384
static constexpr long long O_BL1  = O_W1N + 16384;         // 128
static constexpr long long O_W1R  = O_BL1 + 128;           // 16384
static constexpr long long O_WEN  = O_W1R + 16384;         // 16384
static constexpr long long O_BEN  = O_WEN + 16384;         // 128
static constexpr long long O_WER  = O_BEN + 128;           // 16384
static constexpr long long O_W2N  = O_WER + 16384;         // 16384
static constexpr long long O_BL2  = O_W2N + 16384;         // 128
static constexpr long long O_W2R  = O_BL2 + 128;           // 16384
static constexpr long long O_BASE1= O_W2R + 16384;         // 8192
static constexpr long long O_GRID1= O_BASE1 + 8192;        // 1536
static constexpr long long O_BASE2= O_GRID1 + 1536;        // 128
static constexpr long long O_GRID2= O_BASE2 + 128;         // 768
static constexpr long long O_SW1  = O_GRID2 + 768;         // 65536
static constexpr long long O_SW2  = O_SW1 + 65536;         // 1024
// int region
static constexpr long long I_CNT_UE = O_SW2 + 1024;        // 200000 (cnt_ue,cnt_eu contiguous)
static constexpr long long I_CNT_EU = I_CNT_UE + kNE;      // 100000
static constexpr long long I_RO_UE  = I_CNT_EU + kNU;
static constexpr long long I_RO_EU  = I_RO_UE + kNE;
static constexpr long long I_CUR_UE = I_RO_EU + kNU;
static constexpr long long I_CUR_EU = I_CUR_UE + kNE;
static constexpr long long I_SRT_UE = I_CUR_EU + kNU;
static constexpr long long I_SRT_EU = I_SRT_UE + kE;
static constexpr long long I_BSUM_UE= I_SRT_EU + kE;
static constexpr long long I_BOFF_UE= I_BSUM_UE + 256;
static constexpr long long I_BSUM_EU= I_BOFF_UE + 256;
static constexpr long long I_BOFF_EU= I_BSUM_EU + 256;
// end ~= 67.1M elems = 268 MB

__device__ __forceinline__ float bf2f(unsigned short u) {
    return __uint_as_float(((unsigned)u) << 16);
}

// ---------------- dtype detection ----------------
// grid1[0] as fp32 is deterministically -2.2f (0xC00CCCCD); any other bits => bf16 storage.
__global__ void detect_kernel(const unsigned int* __restrict__ g, int* __restrict__ flag) {
    if (threadIdx.x == 0 && blockIdx.x == 0)
        flag[0] = (g[0] == 0xC00CCCCDu) ? 0 : 1;
}

__global__ __launch_bounds__(256) void zero_kernel(int* __restrict__ p, int n) {
    int i = blockIdx.x * 256 + threadIdx.x;
    if (i < n) p[i] = 0;
}

// ---------------- converts ----------------
struct ConvJobs {
    const void* src[15];
    int off[15];
    int n[15];
};

__global__ __launch_bounds__(256) void convert_jobs_kernel(ConvJobs jobs, float* __restrict__ wsf,
                                                           const int* __restrict__ flag) {
    const int isbf = *flag;
    const int stride = gridDim.x * blockDim.x;
    const int t0 = blockIdx.x * blockDim.x + threadIdx.x;
    for (int t = 0; t < 15; t++) {
        const int n = jobs.n[t];
        const void* s = jobs.src[t];
        float* d = wsf + jobs.off[t];
        for (int i = t0; i < n; i += stride)
            d[i] = isbf ? bf2f(((const unsigned short*)s)[i]) : ((const float*)s)[i];
    }
}

// sw[o][i][j] = spline_w[o][i][j] * scaler[o][i]
__global__ __launch_bounds__(256) void premult_kernel(const void* __restrict__ sp, const void* __restrict__ sc,
                                                      float* __restrict__ dst, int n, const int* __restrict__ flag) {
    const int isbf = *flag;
    const int stride = gridDim.x * blockDim.x;
    for (int i = blockIdx.x * blockDim.x + threadIdx.x; i < n; i += stride) {
        float a = isbf ? bf2f(((const unsigned short*)sp)[i]) : ((const float*)sp)[i];
        float b = isbf ? bf2f(((const unsigned short*)sc)[i >> 3]) : ((const float*)sc)[i >> 3];
        dst[i] = a * b;
    }
}

// ---------------- CSR build ----------------
__global__ __launch_bounds__(256) void hist_kernel(const int* __restrict__ dst, int* __restrict__ cnt, int n) {
    int i = blockIdx.x * 256 + threadIdx.x;
    if (i < n) atomicAdd(&cnt[dst[i]], 1);
}

__global__ __launch_bounds__(256) void scan1_kernel(const int* __restrict__ cnt, int* __restrict__ ro,
                                                    int* __restrict__ bsum, int n) {
    __shared__ int sc[256];
    const int t = threadIdx.x;
    const int i0 = blockIdx.x * 1024 + t * 4;
    int c[4];
#pragma unroll
    for (int q = 0; q < 4; q++) c[q] = (i0 + q < n) ? cnt[i0 + q] : 0;
    int s = c[0] + c[1] + c[2] + c[3];
    sc[t] = s;
    __syncthreads();
    for (int off = 1; off < 256; off <<= 1) {
        int v = (t >= off) ? sc[t - off] : 0;
        __syncthreads();
        sc[t] += v;
        __syncthreads();
    }
    int run = sc[t] - s;  // exclusive
#pragma unroll
    for (int q = 0; q < 4; q++) {
        if (i0 + q < n) ro[i0 + q] = run;
        run += c[q];
    }
    if (t == 255) bsum[blockIdx.x] = sc[255];
}

__global__ __launch_bounds__(256) void scan2_kernel(const int* __restrict__ bsum, int* __restrict__ boff, int nb) {
    __shared__ int sc[256];
    const int t = threadIdx.x;
    int s = (t < nb) ? bsum[t] : 0;
    sc[t] = s;
    __syncthreads();
    for (int off = 1; off < 256; off <<= 1) {
        int v = (t >= off) ? sc[t - off] : 0;
        __syncthreads();
        sc[t] += v;
        __syncthreads();
    }
    if (t < nb) boff[t] = sc[t] - s;
}

__global__ __launch_bounds__(256) void scan3_kernel(int* __restrict__ ro, int* __restrict__ cur,
                                                    const int* __restrict__ boff, int n) {
    const int stride = gridDim.x * blockDim.x;
    for (int i = blockIdx.x * blockDim.x + threadIdx.x; i < n; i += stride) {
        int v = ro[i] + boff[i >> 10];
        ro[i] = v;
        cur[i] = v;
    }
}

__global__ __launch_bounds__(256) void fill_kernel(const int* __restrict__ src, const int* __restrict__ dst,
                                                   int* __restrict__ cur, int* __restrict__ sorted, int n) {
    int i = blockIdx.x * 256 + threadIdx.x;
    if (i < n) {
        int pos = atomicAdd(&cur[dst[i]], 1);
        sorted[pos] = src[i];
    }
}

// ---------------- segment mean (wave per dst row, H=128 => 2 elems/lane) ----------------
template <bool RAWSRC>
__global__ __launch_bounds__(256) void agg_kernel(const void* __restrict__ srcv, float* __restrict__ mean,
                                                  const int* __restrict__ ro, const int* __restrict__ cnt,
                                                  const int* __restrict__ sorted, int Ndst,
                                                  const int* __restrict__ flag) {
    const int lane = threadIdx.x & 63;
    const int n = (blockIdx.x << 2) + (threadIdx.x >> 6);
    if (n >= Ndst) return;
    const int isbf = RAWSRC ? *flag : 0;
    const int beg = ro[n];
    const int deg = cnt[n];
    float ax = 0.f, ay = 0.f;
    for (int p = beg; p < beg + deg; p++) {
        int s = sorted[p];
        if (RAWSRC && isbf) {
            const ushort2 v = *(const ushort2*)((const unsigned short*)srcv + (size_t)s * 128 + lane * 2);
            ax += bf2f(v.x);
            ay += bf2f(v.y);
        } else {
            const float2 v = *(const float2*)((const float*)srcv + (size_t)s * 128 + lane * 2);
            ax += v.x;
            ay += v.y;
        }
    }
    const float inv = (deg > 0) ? 1.f / (float)deg : 0.f;
    *(float2*)&mean[(size_t)n * 128 + lane * 2] = make_float2(ax * inv, ay * inv);
}

// ---------------- fused (dual-)GEMM: out = [relu]( A1@W1^T [+ A2@W2^T] + bias ), 128 outs ----------------
// 64-row tile, 256 threads, 4x8 acc/thread. In-place out==A1 is safe: each block reads only its own
// row-slice of A1/A2 and writes those rows only in the epilogue.
template <int KD, bool RAW1, bool RAW2, bool HASA2, bool RELU>
__global__ __launch_bounds__(256) void lin_kernel(const void* __restrict__ A1v, const void* __restrict__ A2v,
                                                  const float* __restrict__ W1, const float* __restrict__ W2,
                                                  const float* __restrict__ bias, float* __restrict__ out, int N,
                                                  const int* __restrict__ flag) {
    __shared__ float As[32][68];    // [k][row], stride 68 -> 16B-aligned float4 reads
    __shared__ float Ws[32][132];   // [k][o]
    const int tid = threadIdx.x;
    const int r0 = blockIdx.x * 64;
    const int tr = tid >> 4;   // rows tr*4..+3
    const int tc = tid & 15;   // outs tc*8..+7
    float acc[4][8];
#pragma unroll
    for (int r = 0; r < 4; r++)
#pragma unroll
        for (int c = 0; c < 8; c++) acc[r][c] = 0.f;

    const int isbf = (RAW1 || RAW2) ? *flag : 0;
    const int srow = tid >> 2;          // 0..63
    const int skq = (tid & 3) * 8;      // 0,8,16,24
    const int wo = tid >> 1;            // 0..127
    const int wh = (tid & 1) * 16;

    const int nph = HASA2 ? 2 : 1;
    for (int ph = 0; ph < nph; ph++) {
        const void* Av = (ph == 0) ? A1v : A2v;
        const bool raw = (ph == 0) ? RAW1 : RAW2;
        const float* W = (ph == 0) ? W1 : W2;
#pragma unroll 1
        for (int kb = 0; kb < KD; kb += 32) {
            {  // stage A transposed
                const int grow = r0 + srow;
                float v[8];
                if (grow < N) {
                    if (raw && isbf) {
                        const unsigned short* p = (const unsigned short*)Av + (size_t)grow * KD + kb + skq;
#pragma unroll
                        for (int c = 0; c < 8; c++) v[c] = bf2f(p[c]);
                    } else {
                        const float* p = (const float*)Av + (size_t)grow * KD + kb + skq;
#pragma unroll
                        for (int c = 0; c < 8; c++) v[c] = p[c];
                    }
                } else {
#pragma unroll
                    for (int c = 0; c < 8; c++) v[c] = 0.f;
                }
#pragma unroll
                for (int c = 0; c < 8; c++) As[skq + c][srow] = v[c];
            }
            {  // stage W transposed (fp32 converted weights)
#pragma unroll
                for (int q = 0; q < 4; q++) {
                    float4 w = *(const float4*)&W[(size_t)wo * KD + kb + wh + q * 4];
                    Ws[wh + q * 4 + 0][wo] = w.x;
                    Ws[wh + q * 4 + 1][wo] = w.y;
                    Ws[wh + q * 4 + 2][wo] = w.z;
                    Ws[wh + q * 4 + 3][wo] = w.w;
                }
            }
            __syncthreads();
#pragma unroll
            for (int k = 0; k < 32; k++) {
                float4 a = *(const float4*)&As[k][tr * 4];
                float4 w0 = *(const float4*)&Ws[k][tc * 8];
                float4 w1 = *(const float4*)&Ws[k][tc * 8 + 4];
                float av[4] = {a.x, a.y, a.z, a.w};
                float wv[8] = {w0.x, w0.y, w0.z, w0.w, w1.x, w1.y, w1.z, w1.w};
#pragma unroll
                for (int r = 0; r < 4; r++)
#pragma unroll
                    for (int c = 0; c < 8; c++) acc[r][c] = fmaf(av[r], wv[c], acc[r][c]);
            }
            __syncthreads();
        }
    }
    float bv[8];
#pragma unroll
    for (int c = 0; c < 8; c++) bv[c] = bias[tc * 8 + c];
#pragma unroll
    for (int r = 0; r < 4; r++) {
        int grow = r0 + tr * 4 + r;
        if (grow < N) {
            float o[8];
#pragma unroll
            for (int c = 0; c < 8; c++) {
                float v = acc[r][c] + bv[c];
                o[c] = RELU ? fmaxf(v, 0.f) : v;
            }
            float4* dst = (float4*)&out[(size_t)grow * 128 + tc * 8];
            dst[0] = make_float4(o[0], o[1], o[2], o[3]);
            dst[1] = make_float4(o[4], o[5], o[6], o[7]);
        }
    }
}

// ---------------- Cox-de Boor (K=3, 12 knots -> 8 bases), compact reciprocals ----------------
// r1[m]=1/(t[m+1]-t[m]) (11), r2[m]=1/(t[m+2]-t[m]) (10), r3[m]=1/(t[m+3]-t[m]) (9);
// the "b" denominators are just shifted: 1/(t[m+2]-t[m+1]) = r1[m+1], etc.
__device__ __forceinline__ void bases8(float x, const float* __restrict__ t, const float* __restrict__ r1,
                                       const float* __restrict__ r2, const float* __restrict__ r3,
                                       float* __restrict__ b) {
    float bb[11];
#pragma unroll
    for (int m = 0; m < 11; m++) bb[m] = (x >= t[m] && x < t[m + 1]) ? 1.f : 0.f;
#pragma unroll
    for (int m = 0; m < 10; m++) bb[m] = (x - t[m]) * r1[m] * bb[m] + (t[m + 2] - x) * r1[m + 1] * bb[m + 1];
#pragma unroll
    for (int m = 0; m < 9; m++) bb[m] = (x - t[m]) * r2[m] * bb[m] + (t[m + 3] - x) * r2[m + 1] * bb[m + 1];
#pragma unroll
    for (int m = 0; m < 8; m++) b[m] = (x - t[m]) * r3[m] * bb[m] + (t[m + 4] - x) * r3[m + 1] * bb[m + 1];
}

// ---------------- KAN layer 1: [NE,128] -> [NE,64], h = silu(x)@baseW^T + B(x)@sw^T ----------------
// LDS: RD 21504 + Bs 17408 + Ws 16384 = 55296 B (< 64 KB)
__global__ __launch_bounds__(256) void kan1_kernel(const float* __restrict__ X, const float* __restrict__ baseW,
                                                   const float* __restrict__ sw, const float* __restrict__ grid,
                                                   float* __restrict__ Hout) {
    __shared__ float RD[128][42];  // per-feature: t[12]@0, r1[11]@12, r2[10]@23, r3[9]@33
    __shared__ float Bs[64][68];   // [k][row] (phase A uses first 32 k-rows)
    __shared__ float Ws[64][64];   // [k][o]
    const int tid = threadIdx.x;
    const int r0 = blockIdx.x * 64;

    if (tid < 128) {
        float t[12];
#pragma unroll
        for (int j = 0; j < 12; j++) t[j] = grid[tid * 12 + j];
#pragma unroll
        for (int j = 0; j < 12; j++) RD[tid][j] = t[j];
#pragma unroll
        for (int m = 0; m < 11; m++) RD[tid][12 + m] = 1.f / (t[m + 1] - t[m]);
#pragma unroll
        for (int m = 0; m < 10; m++) RD[tid][23 + m] = 1.f / (t[m + 2] - t[m]);
#pragma unroll
        for (int m = 0; m < 9; m++) RD[tid][33 + m] = 1.f / (t[m + 3] - t[m]);
    }
    __syncthreads();

    const int tr = tid >> 4;  // rows tr*4..+3
    const int tc = tid & 15;  // outs tc*4..+3
    float acc[4][4];
#pragma unroll
    for (int r = 0; r < 4; r++)
#pragma unroll
        for (int c = 0; c < 4; c++) acc[r][c] = 0.f;

    // phase A: silu(x) @ baseW^T (K=128)
    {
        const int srow = tid >> 2;
        const int skq = (tid & 3) * 8;
        float(*As)[68] = Bs;
#pragma unroll 1
        for (int kb = 0; kb < 128; kb += 32) {
            {
                const float* p = &X[(size_t)(r0 + srow) * 128 + kb + skq];
#pragma unroll
                for (int c = 0; c < 8; c++) {
                    float x = p[c];
                    As[skq + c][srow] = x / (1.f + __expf(-x));
                }
            }
            {
                const int o = tid >> 2;
                const int kq = (tid & 3) * 8;
#pragma unroll
                for (int c = 0; c < 8; c++) Ws[kq + c][o] = baseW[(size_t)o * 128 + kb + kq + c];
            }
            __syncthreads();
#pragma unroll
            for (int k = 0; k < 32; k++) {
                float4 a = *(const float4*)&As[k][tr * 4];
                float4 w = *(const float4*)&Ws[k][tc * 4];
                float av[4] = {a.x, a.y, a.z, a.w};
                float wv[4] = {w.x, w.y, w.z, w.w};
#pragma unroll
                for (int r = 0; r < 4; r++)
#pragma unroll
                    for (int c = 0; c < 4; c++) acc[r][c] = fmaf(av[r], wv[c], acc[r][c]);
            }
            __syncthreads();
        }
    }

    // phase B: spline GEMM over flattened (i,j); 8 features/chunk, k = j*8+il
#pragma unroll 1
    for (int ib = 0; ib < 128; ib += 8) {
#pragma unroll
        for (int s = 0; s < 2; s++) {
            int p = tid + 256 * s;
            int il = p & 7, row = p >> 3;
            int i = ib + il;
            float x = X[(size_t)(r0 + row) * 128 + i];
            float b[8];
            bases8(x, &RD[i][0], &RD[i][12], &RD[i][23], &RD[i][33], b);
#pragma unroll
            for (int j = 0; j < 8; j++) Bs[j * 8 + il][row] = b[j];
        }
        {
            const int o = tid >> 2;
            const int q = tid & 3;
#pragma unroll
            for (int f = 0; f < 4; f++) {
                int w = q * 16 + f * 4;
                float4 v = *(const float4*)&sw[(size_t)o * 1024 + ib * 8 + w];
                float vv[4] = {v.x, v.y, v.z, v.w};
#pragma unroll
                for (int c = 0; c < 4; c++) {
                    int widx = w + c;           // = il*8 + j
                    int il = widx >> 3, j = widx & 7;
                    Ws[j * 8 + il][o] = vv[c];
                }
            }
        }
        __syncthreads();
#pragma unroll
        for (int k = 0; k < 64; k++) {
            float4 a = *(const float4*)&Bs[k][tr * 4];
            float4 w = *(const float4*)&Ws[k][tc * 4];
            float av[4] = {a.x, a.y, a.z, a.w};
            float wv[4] = {w.x, w.y, w.z, w.w};
#pragma unroll
            for (int r = 0; r < 4; r++)
#pragma unroll
                for (int c = 0; c < 4; c++) acc[r][c] = fmaf(av[r], wv[c], acc[r][c]);
        }
        __syncthreads();
    }

#pragma unroll
    for (int r = 0; r < 4; r++) {
        int grow = r0 + tr * 4 + r;
        *(float4*)&Hout[(size_t)grow * 64 + tc * 4] = make_float4(acc[r][0], acc[r][1], acc[r][2], acc[r][3]);
    }
}

// ---------------- KAN layer 2: [NE,64] -> [NE,2]; wave per row, lane per feature ----------------
__global__ __launch_bounds__(256) void kan2_kernel(const float* __restrict__ h, const float* __restrict__ base2,
                                                   const float* __restrict__ sw2, const float* __restrict__ grid2,
                                                   void* __restrict__ out, const int* __restrict__ flag) {
    const int lane = threadIdx.x & 63;
    const int wid = (blockIdx.x * blockDim.x + threadIdx.x) >> 6;
    const int nw = (gridDim.x * blockDim.x) >> 6;
    const int k = lane;
    float t[12];
#pragma unroll
    for (int j = 0; j < 12; j++) t[j] = grid2[k * 12 + j];
    float r1[11], r2[10], r3[9];
#pragma unroll
    for (int m = 0; m < 11; m++) r1[m] = 1.f / (t[m + 1] - t[m]);
#pragma unroll
    for (int m = 0; m < 10; m++) r2[m] = 1.f / (t[m + 2] - t[m]);
#pragma unroll
    for (int m = 0; m < 9; m++) r3[m] = 1.f / (t[m + 3] - t[m]);
    const float wb0 = base2[k], wb1 = base2[64 + k];
    float ws0[8], ws1[8];
#pragma unroll
    for (int j = 0; j < 8; j++) { ws0[j] = sw2[k * 8 + j]; ws1[j] = sw2[512 + k * 8 + j]; }
    const int isbf = *flag;

    for (int n = wid; n < kNE; n += nw) {
        float x = h[(size_t)n * 64 + k];
        float sil = x / (1.f + __expf(-x));
        float b[8];
        bases8(x, t, r1, r2, r3, b);
        float o0 = sil * wb0, o1 = sil * wb1;
#pragma unroll
        for (int j = 0; j < 8; j++) {
            o0 = fmaf(b[j], ws0[j], o0);
            o1 = fmaf(b[j], ws1[j], o1);
        }
#pragma unroll
        for (int off = 32; off > 0; off >>= 1) {
            o0 += __shfl_down(o0, off, 64);
            o1 += __shfl_down(o1, off, 64);
        }
        if (lane == 0) {
            if (isbf) {
                __hip_bfloat16* ob = (__hip_bfloat16*)out;
                ob[(size_t)n * 2] = __float2bfloat16(o0);
                ob[(size_t)n * 2 + 1] = __float2bfloat16(o1);
            } else {
                ((float2*)out)[n] = make_float2(o0, o1);
            }
        }
    }
}

// ---------------- launch ----------------
extern "C" void kernel_launch(void* const* d_in, const int* in_sizes, int n_in, void* d_out, int out_size,
                              void* d_ws, size_t ws_size, hipStream_t stream) {
    (void)in_sizes; (void)n_in; (void)out_size; (void)ws_size;
    float* wsf = (float*)d_ws;
    int* wsi = (int*)d_ws;

    // zero edge-count histograms (cnt_ue, cnt_eu contiguous)
    zero_kernel<<<(kNE + kNU + 255) / 256, 256, 0, stream>>>(wsi + I_CNT_UE, kNE + kNU);

    // dtype flag
    detect_kernel<<<1, 64, 0, stream>>>((const unsigned int*)d_in[21], wsi + O_FLAG);

    // convert small fp tensors to fp32 workspace copies
    ConvJobs jobs;
    const int srcIdx[15] = {3, 4, 6, 7, 8, 9, 10, 11, 12, 13, 14, 18, 21, 22, 25};
    const long long dstOff[15] = {O_WEM, O_BEM, O_W1N, O_BL1, O_W1R, O_WEN, O_BEN, O_WER,
                                  O_W2N, O_BL2, O_W2R, O_BASE1, O_GRID1, O_BASE2, O_GRID2};
    const int cnts[15] = {8192, 128, 16384, 128, 16384, 16384, 128, 16384, 16384, 128, 16384, 8192, 1536, 128, 768};
    for (int t = 0; t < 15; t++) {
        jobs.src[t] = d_in[srcIdx[t]];
        jobs.off[t] = (int)dstOff[t];
        jobs.n[t] = cnts[t];
    }
    convert_jobs_kernel<<<64, 256, 0, stream>>>(jobs, wsf, wsi + O_FLAG);
    premult_kernel<<<64, 256, 0, stream>>>(d_in[19], d_in[20], wsf + O_SW1, 65536, wsi + O_FLAG);
    premult_kernel<<<4, 256, 0, stream>>>(d_in[23], d_in[24], wsf + O_SW2, 1024, wsi + O_FLAG);

    const int* ei_ue = (const int*)d_in[1];
    const int* ei_eu = (const int*)d_in[2];
    const int egrid = (kE + 255) / 256;

    // CSR build: ue (dst=emails), eu (dst=users)
    hist_kernel<<<egrid, 256, 0, stream>>>(ei_ue + kE, wsi + I_CNT_UE, kE);
    hist_kernel<<<egrid, 256, 0, stream>>>(ei_eu + kE, wsi + I_CNT_EU, kE);
    scan1_kernel<<<196, 256, 0, stream>>>(wsi + I_CNT_UE, wsi + I_RO_UE, wsi + I_BSUM_UE, kNE);
    scan2_kernel<<<1, 256, 0, stream>>>(wsi + I_BSUM_UE, wsi + I_BOFF_UE, 196);
    scan3_kernel<<<512, 256, 0, stream>>>(wsi + I_RO_UE, wsi + I_CUR_UE, wsi + I_BOFF_UE, kNE);
    scan1_kernel<<<98, 256, 0, stream>>>(wsi + I_CNT_EU, wsi + I_RO_EU, wsi + I_BSUM_EU, kNU);
    scan2_kernel<<<1, 256, 0, stream>>>(wsi + I_BSUM_EU, wsi + I_BOFF_EU, 98);
    scan3_kernel<<<512, 256, 0, stream>>>(wsi + I_RO_EU, wsi + I_CUR_EU, wsi + I_BOFF_EU, kNU);
    fill_kernel<<<egrid, 256, 0, stream>>>(ei_ue, ei_ue + kE, wsi + I_CUR_UE, wsi + I_SRT_UE, kE);
    fill_kernel<<<egrid, 256, 0, stream>>>(ei_eu, ei_eu + kE, wsi + I_CUR_EU, wsi + I_SRT_EU, kE);

    // 1. xe = x_email @ w_email^T + b_email   -> B0
    lin_kernel<64, true, false, false, false><<<3125, 256, 0, stream>>>(
        d_in[0], nullptr, wsf + O_WEM, nullptr, wsf + O_BEM, wsf + O_B0, kNE, wsi + O_FLAG);

    // 2. mean_ue1 = agg(emb_user bf16) -> B1
    agg_kernel<true><<<kNE / 4, 256, 0, stream>>>(d_in[5], wsf + O_B1, wsi + I_RO_UE, wsi + I_CNT_UE,
                                                  wsi + I_SRT_UE, kNE, wsi + O_FLAG);
    // 3. e1 = relu(lin(B1) + lin(xe=B0)) -> B1 in-place
    lin_kernel<128, false, false, true, true><<<3125, 256, 0, stream>>>(
        wsf + O_B1, wsf + O_B0, wsf + O_W1N, wsf + O_W1R, wsf + O_BL1, wsf + O_B1, kNE, wsi + O_FLAG);

    // 4. mean_eu = agg(xe=B0) -> B2
    agg_kernel<false><<<kNU / 4, 256, 0, stream>>>(wsf + O_B0, wsf + O_B2, wsi + I_RO_EU, wsi + I_CNT_EU,
                                                   wsi + I_SRT_EU, kNU, wsi + O_FLAG);
    // 5. u1 = relu(lin(B2) + lin(emb bf16)) -> B2 in-place.  B0 now free.
    lin_kernel<128, false, true, true, true><<<1563, 256, 0, stream>>>(
        wsf + O_B2, d_in[5], wsf + O_WEN, wsf + O_WER, wsf + O_BEN, wsf + O_B2, kNU, wsi + O_FLAG);

    // 6. mean_ue2 = agg(u1=B2) -> B0
    agg_kernel<false><<<kNE / 4, 256, 0, stream>>>(wsf + O_B2, wsf + O_B0, wsi + I_RO_UE, wsi + I_CNT_UE,
                                                   wsi + I_SRT_UE, kNE, wsi + O_FLAG);
    // 7. e2 = relu(lin(B0) + lin(e1=B1)) -> B0 in-place.  B1 now free.
    lin_kernel<128, false, false, true, true><<<3125, 256, 0, stream>>>(
        wsf + O_B0, wsf + O_B1, wsf + O_W2N, wsf + O_W2R, wsf + O_BL2, wsf + O_B0, kNE, wsi + O_FLAG);

    // 8. h = kan1(e2=B0) -> B1 (first NE*64 elems)
    kan1_kernel<<<3125, 256, 0, stream>>>(wsf + O_B0, wsf + O_BASE1, wsf + O_SW1, wsf + O_GRID1, wsf + O_B1);
    // 9. out = kan2(h=B1)
    kan2_kernel<<<2048, 256, 0, stream>>>(wsf + O_B1, wsf + O_BASE2, wsf + O_SW2, wsf + O_GRID2, d_out,
                                          wsi + O_FLAG);
}

// Round 6
// 1650.390 us; speedup vs baseline: 1.2679x; 1.2679x over previous
//
#include <hip/hip_runtime.h>
#include <hip/hip_bf16.h>

typedef __attribute__((ext_vector_type(8))) short short8;
typedef __attribute__((ext_vector_type(4))) float f32x4;

// ---------------- problem constants ----------------
static constexpr int kNE  = 200000;   // emails
static constexpr int kNU  = 100000;   // users
static constexpr int kE   = 1000000;  // edges per type

// ---------------- workspace layout (4-byte element offsets) ----------------
// HARD CONSTRAINT (discovered r5): ws_size = 256 MiB = 268,435,456 B. This layout ends at
// 268,324,736 B (110 KB margin). Do not append without removing something.
static constexpr long long O_FLAG = 0;                     // int flag (64 reserved)
static constexpr long long SZ_NEH = (long long)kNE * 128;  // 25.6M
static constexpr long long SZ_NUH = (long long)kNU * 128;  // 12.8M
static constexpr long long O_B0   = 64;
static constexpr long long O_B1   = O_B0 + SZ_NEH;
static constexpr long long O_B2   = O_B1 + SZ_NEH;
static constexpr long long O_W    = O_B2 + SZ_NUH;
static constexpr long long O_WEM  = O_W;                   // 8192
static constexpr long long O_BEM  = O_WEM + 8192;          // 128
static constexpr long long O_W1N  = O_BEM + 128;           // 16384
static constexpr long long O_BL1  = O_W1N + 16384;         // 128
static constexpr long long O_W1R  = O_BL1 + 128;           // 16384
static constexpr long long O_WEN  = O_W1R + 16384;         // 16384
static constexpr long long O_BEN  = O_WEN + 16384;         // 128
static constexpr long long O_WER  = O_BEN + 128;           // 16384
static constexpr long long O_W2N  = O_WER + 16384;         // 16384
static constexpr long long O_BL2  = O_W2N + 16384;         // 128
static constexpr long long O_W2R  = O_BL2 + 128;           // 16384
static constexpr long long O_GRID1= O_W2R + 16384;         // 1536
static constexpr long long O_BASE2= O_GRID1 + 1536;        // 128
static constexpr long long O_GRID2= O_BASE2 + 128;         // 768
static constexpr long long O_SW2  = O_GRID2 + 768;         // 1024
// int region
static constexpr long long I_CNT_UE = O_SW2 + 1024;        // cnt_ue,cnt_eu contiguous
static constexpr long long I_CNT_EU = I_CNT_UE + kNE;
static constexpr long long I_RO_UE  = I_CNT_EU + kNU;
static constexpr long long I_RO_EU  = I_RO_UE + kNE;
static constexpr long long I_CUR_UE = I_RO_EU + kNU;
static constexpr long long I_CUR_EU = I_CUR_UE + kNE;
static constexpr long long I_SRT_UE = I_CUR_EU + kNU;
static constexpr long long I_SRT_EU = I_SRT_UE + kE;
static constexpr long long I_BSUM_UE= I_SRT_EU + kE;
static constexpr long long I_BOFF_UE= I_BSUM_UE + 256;
static constexpr long long I_BSUM_EU= I_BOFF_UE + 256;
static constexpr long long I_BOFF_EU= I_BSUM_EU + 256;
static constexpr long long FR_BASE_I= (I_BOFF_EU + 256 + 7) & ~7LL;  // 16B-aligned
// bf16 MFMA B-fragment region (ushort offsets from fbase)
static constexpr long long U_BASE1 = 0;                // [64][128]  exact bf16 -> 8192
static constexpr long long U_SW1H  = U_BASE1 + 8192;   // [64][1024] hi -> 65536
static constexpr long long U_SW1L  = U_SW1H + 65536;   // lo -> 65536

__device__ __forceinline__ float bf2f(unsigned short u) {
    return __uint_as_float(((unsigned)u) << 16);
}
__device__ __forceinline__ unsigned short f2bf_rne(float f) {
    unsigned u = __float_as_uint(f);
    return (unsigned short)((u + 0x7fffu + ((u >> 16) & 1u)) >> 16);
}
__device__ __forceinline__ void split2(float x, unsigned short& hi, unsigned short& lo) {
    hi = f2bf_rne(x);
    lo = f2bf_rne(x - bf2f(hi));
}

// ---------------- dtype detection ----------------
__global__ void detect_kernel(const unsigned int* __restrict__ g, int* __restrict__ flag) {
    if (threadIdx.x == 0 && blockIdx.x == 0)
        flag[0] = (g[0] == 0xC00CCCCDu) ? 0 : 1;
}

__global__ __launch_bounds__(256) void zero_kernel(int* __restrict__ p, int n) {
    int i = blockIdx.x * 256 + threadIdx.x;
    if (i < n) p[i] = 0;
}

// ---------------- converts ----------------
struct ConvJobs {
    const void* src[14];
    int off[14];
    int n[14];
};

__global__ __launch_bounds__(256) void convert_jobs_kernel(ConvJobs jobs, float* __restrict__ wsf,
                                                           const int* __restrict__ flag) {
    const int isbf = *flag;
    const int stride = gridDim.x * blockDim.x;
    const int t0 = blockIdx.x * blockDim.x + threadIdx.x;
    for (int t = 0; t < 14; t++) {
        const int n = jobs.n[t];
        const void* s = jobs.src[t];
        float* d = wsf + jobs.off[t];
        for (int i = t0; i < n; i += stride)
            d[i] = isbf ? bf2f(((const unsigned short*)s)[i]) : ((const float*)s)[i];
    }
}

// sw2[o][i][j] = spline_w[o][i][j] * scaler[o][i]  (fp32, for kan2)
__global__ __launch_bounds__(256) void premult_kernel(const void* __restrict__ sp, const void* __restrict__ sc,
                                                      float* __restrict__ dst, int n, const int* __restrict__ flag) {
    const int isbf = *flag;
    const int stride = gridDim.x * blockDim.x;
    for (int i = blockIdx.x * blockDim.x + threadIdx.x; i < n; i += stride) {
        float a = isbf ? bf2f(((const unsigned short*)sp)[i]) : ((const float*)sp)[i];
        float b = isbf ? bf2f(((const unsigned short*)sc)[i >> 3]) : ((const float*)sc)[i >> 3];
        dst[i] = a * b;
    }
}

// ---------------- kan1 B-fragment packs ----------------
// frag element: dst[((kt*4 + nt)*64 + lane)*8 + j] = W[nt*16 + (lane&15)][kt*32 + (lane>>4)*8 + j]
__global__ __launch_bounds__(256) void frag_base1_kernel(const void* __restrict__ src,
                                                         unsigned short* __restrict__ dst,
                                                         const int* __restrict__ flag) {
    const int t = blockIdx.x * 256 + threadIdx.x;  // 4*4*64 = 1024
    if (t >= 1024) return;
    const int isbf = *flag;
    const int lane = t & 63, nt = (t >> 6) & 3, kt = t >> 8;
    const int n = nt * 16 + (lane & 15);
    const int k0 = kt * 32 + (lane >> 4) * 8;
    unsigned short* d = dst + (((size_t)(kt * 4 + nt) * 64 + lane) << 3);
#pragma unroll
    for (int j = 0; j < 8; j++) {
        float f = isbf ? bf2f(((const unsigned short*)src)[n * 128 + k0 + j])
                       : ((const float*)src)[n * 128 + k0 + j];
        d[j] = f2bf_rne(f);  // exact when storage is bf16
    }
}

// sw1 = spline*scaler split into hi/lo bf16 frags (K=1024, O=64)
__global__ __launch_bounds__(256) void frag_sw1_kernel(const void* __restrict__ sp, const void* __restrict__ sc,
                                                       unsigned short* __restrict__ dh,
                                                       unsigned short* __restrict__ dl,
                                                       const int* __restrict__ flag) {
    const int t = blockIdx.x * 256 + threadIdx.x;  // 32*4*64 = 8192
    if (t >= 8192) return;
    const int isbf = *flag;
    const int lane = t & 63, nt = (t >> 6) & 3, kt = t >> 8;
    const int n = nt * 16 + (lane & 15);
    const int k0 = kt * 32 + (lane >> 4) * 8;
    const float scal = isbf ? bf2f(((const unsigned short*)sc)[n * 128 + (k0 >> 3)])
                            : ((const float*)sc)[n * 128 + (k0 >> 3)];
    const size_t base = ((size_t)(kt * 4 + nt) * 64 + lane) << 3;
#pragma unroll
    for (int j = 0; j < 8; j++) {
        float f = isbf ? bf2f(((const unsigned short*)sp)[(size_t)n * 1024 + k0 + j])
                       : ((const float*)sp)[(size_t)n * 1024 + k0 + j];
        float p = f * scal;
        unsigned short hi, lo;
        split2(p, hi, lo);
        dh[base + j] = hi;
        dl[base + j] = lo;
    }
}

// ---------------- CSR build ----------------
__global__ __launch_bounds__(256) void hist_kernel(const int* __restrict__ dst, int* __restrict__ cnt, int n) {
    int i = blockIdx.x * 256 + threadIdx.x;
    if (i < n) atomicAdd(&cnt[dst[i]], 1);
}

__global__ __launch_bounds__(256) void scan1_kernel(const int* __restrict__ cnt, int* __restrict__ ro,
                                                    int* __restrict__ bsum, int n) {
    __shared__ int sc[256];
    const int t = threadIdx.x;
    const int i0 = blockIdx.x * 1024 + t * 4;
    int c[4];
#pragma unroll
    for (int q = 0; q < 4; q++) c[q] = (i0 + q < n) ? cnt[i0 + q] : 0;
    int s = c[0] + c[1] + c[2] + c[3];
    sc[t] = s;
    __syncthreads();
    for (int off = 1; off < 256; off <<= 1) {
        int v = (t >= off) ? sc[t - off] : 0;
        __syncthreads();
        sc[t] += v;
        __syncthreads();
    }
    int run = sc[t] - s;  // exclusive
#pragma unroll
    for (int q = 0; q < 4; q++) {
        if (i0 + q < n) ro[i0 + q] = run;
        run += c[q];
    }
    if (t == 255) bsum[blockIdx.x] = sc[255];
}

__global__ __launch_bounds__(256) void scan2_kernel(const int* __restrict__ bsum, int* __restrict__ boff, int nb) {
    __shared__ int sc[256];
    const int t = threadIdx.x;
    int s = (t < nb) ? bsum[t] : 0;
    sc[t] = s;
    __syncthreads();
    for (int off = 1; off < 256; off <<= 1) {
        int v = (t >= off) ? sc[t - off] : 0;
        __syncthreads();
        sc[t] += v;
        __syncthreads();
    }
    if (t < nb) boff[t] = sc[t] - s;
}

__global__ __launch_bounds__(256) void scan3_kernel(int* __restrict__ ro, int* __restrict__ cur,
                                                    const int* __restrict__ boff, int n) {
    const int stride = gridDim.x * blockDim.x;
    for (int i = blockIdx.x * blockDim.x + threadIdx.x; i < n; i += stride) {
        int v = ro[i] + boff[i >> 10];
        ro[i] = v;
        cur[i] = v;
    }
}

__global__ __launch_bounds__(256) void fill_kernel(const int* __restrict__ src, const int* __restrict__ dst,
                                                   int* __restrict__ cur, int* __restrict__ sorted, int n) {
    int i = blockIdx.x * 256 + threadIdx.x;
    if (i < n) {
        int pos = atomicAdd(&cur[dst[i]], 1);
        sorted[pos] = src[i];
    }
}

// ---------------- segment mean (wave per dst row) ----------------
template <bool RAWSRC>
__global__ __launch_bounds__(256) void agg_kernel(const void* __restrict__ srcv, float* __restrict__ mean,
                                                  const int* __restrict__ ro, const int* __restrict__ cnt,
                                                  const int* __restrict__ sorted, int Ndst,
                                                  const int* __restrict__ flag) {
    const int lane = threadIdx.x & 63;
    const int n = (blockIdx.x << 2) + (threadIdx.x >> 6);
    if (n >= Ndst) return;
    const int isbf = RAWSRC ? *flag : 0;
    const int beg = ro[n];
    const int deg = cnt[n];
    float ax = 0.f, ay = 0.f;
    for (int p = beg; p < beg + deg; p++) {
        int s = sorted[p];
        if (RAWSRC && isbf) {
            const ushort2 v = *(const ushort2*)((const unsigned short*)srcv + (size_t)s * 128 + lane * 2);
            ax += bf2f(v.x);
            ay += bf2f(v.y);
        } else {
            const float2 v = *(const float2*)((const float*)srcv + (size_t)s * 128 + lane * 2);
            ax += v.x;
            ay += v.y;
        }
    }
    const float inv = (deg > 0) ? 1.f / (float)deg : 0.f;
    *(float2*)&mean[(size_t)n * 128 + lane * 2] = make_float2(ax * inv, ay * inv);
}

// ---------------- fp32 (dual-)GEMM (round-2 known-good): out = [relu](A1@W1^T [+ A2@W2^T] + b) ----------------
template <int KD, bool RAW1, bool RAW2, bool HASA2, bool RELU>
__global__ __launch_bounds__(256) void lin_kernel(const void* __restrict__ A1v, const void* __restrict__ A2v,
                                                  const float* __restrict__ W1, const float* __restrict__ W2,
                                                  const float* __restrict__ bias, float* __restrict__ out, int N,
                                                  const int* __restrict__ flag) {
    __shared__ float As[32][68];
    __shared__ float Ws[32][132];
    const int tid = threadIdx.x;
    const int r0 = blockIdx.x * 64;
    const int tr = tid >> 4;
    const int tc = tid & 15;
    float acc[4][8];
#pragma unroll
    for (int r = 0; r < 4; r++)
#pragma unroll
        for (int c = 0; c < 8; c++) acc[r][c] = 0.f;

    const int isbf = (RAW1 || RAW2) ? *flag : 0;
    const int srow = tid >> 2;
    const int skq = (tid & 3) * 8;
    const int wo = tid >> 1;
    const int wh = (tid & 1) * 16;

    const int nph = HASA2 ? 2 : 1;
    for (int ph = 0; ph < nph; ph++) {
        const void* Av = (ph == 0) ? A1v : A2v;
        const bool raw = (ph == 0) ? RAW1 : RAW2;
        const float* W = (ph == 0) ? W1 : W2;
#pragma unroll 1
        for (int kb = 0; kb < KD; kb += 32) {
            {
                const int grow = r0 + srow;
                float v[8];
                if (grow < N) {
                    if (raw && isbf) {
                        const unsigned short* p = (const unsigned short*)Av + (size_t)grow * KD + kb + skq;
#pragma unroll
                        for (int c = 0; c < 8; c++) v[c] = bf2f(p[c]);
                    } else {
                        const float* p = (const float*)Av + (size_t)grow * KD + kb + skq;
#pragma unroll
                        for (int c = 0; c < 8; c++) v[c] = p[c];
                    }
                } else {
#pragma unroll
                    for (int c = 0; c < 8; c++) v[c] = 0.f;
                }
#pragma unroll
                for (int c = 0; c < 8; c++) As[skq + c][srow] = v[c];
            }
            {
#pragma unroll
                for (int q = 0; q < 4; q++) {
                    float4 w = *(const float4*)&W[(size_t)wo * KD + kb + wh + q * 4];
                    Ws[wh + q * 4 + 0][wo] = w.x;
                    Ws[wh + q * 4 + 1][wo] = w.y;
                    Ws[wh + q * 4 + 2][wo] = w.z;
                    Ws[wh + q * 4 + 3][wo] = w.w;
                }
            }
            __syncthreads();
#pragma unroll
            for (int k = 0; k < 32; k++) {
                float4 a = *(const float4*)&As[k][tr * 4];
                float4 w0 = *(const float4*)&Ws[k][tc * 8];
                float4 w1 = *(const float4*)&Ws[k][tc * 8 + 4];
                float av[4] = {a.x, a.y, a.z, a.w};
                float wv[8] = {w0.x, w0.y, w0.z, w0.w, w1.x, w1.y, w1.z, w1.w};
#pragma unroll
                for (int r = 0; r < 4; r++)
#pragma unroll
                    for (int c = 0; c < 8; c++) acc[r][c] = fmaf(av[r], wv[c], acc[r][c]);
            }
            __syncthreads();
        }
    }
    float bv[8];
#pragma unroll
    for (int c = 0; c < 8; c++) bv[c] = bias[tc * 8 + c];
#pragma unroll
    for (int r = 0; r < 4; r++) {
        int grow = r0 + tr * 4 + r;
        if (grow < N) {
            float o[8];
#pragma unroll
            for (int c = 0; c < 8; c++) {
                float v = acc[r][c] + bv[c];
                o[c] = RELU ? fmaxf(v, 0.f) : v;
            }
            float4* dst = (float4*)&out[(size_t)grow * 128 + tc * 8];
            dst[0] = make_float4(o[0], o[1], o[2], o[3]);
            dst[1] = make_float4(o[4], o[5], o[6], o[7]);
        }
    }
}

// ---------------- Cox-de Boor, compact reciprocals (round-2 verified) ----------------
__device__ __forceinline__ void bases8(float x, const float* __restrict__ t, const float* __restrict__ r1,
                                       const float* __restrict__ r2, const float* __restrict__ r3,
                                       float* __restrict__ b) {
    float bb[11];
#pragma unroll
    for (int m = 0; m < 11; m++) bb[m] = (x >= t[m] && x < t[m + 1]) ? 1.f : 0.f;
#pragma unroll
    for (int m = 0; m < 10; m++) bb[m] = (x - t[m]) * r1[m] * bb[m] + (t[m + 2] - x) * r1[m + 1] * bb[m + 1];
#pragma unroll
    for (int m = 0; m < 9; m++) bb[m] = (x - t[m]) * r2[m] * bb[m] + (t[m + 3] - x) * r2[m + 1] * bb[m + 1];
#pragma unroll
    for (int m = 0; m < 8; m++) b[m] = (x - t[m]) * r3[m] * bb[m] + (t[m + 4] - x) * r3[m + 1] * bb[m + 1];
}

// ---------------- KAN layer 1 (MFMA, fully split): [NE,128] -> [NE,64] ----------------
// Per-feature knots from LDS (round-2 values); bases & silu split into hi/lo bf16;
// sw1 weights split into hi/lo B-frags: acc += bh@wh + bl@wh + bh@wl  (~fp32 quality).
__global__ __launch_bounds__(256) void kan1_mfma(const float* __restrict__ X,
                                                 const unsigned short* __restrict__ basef,
                                                 const unsigned short* __restrict__ swh,
                                                 const unsigned short* __restrict__ swl,
                                                 const float* __restrict__ grid, float* __restrict__ Hout) {
    __shared__ float RD[128][42];  // t[12]@0, r1[11]@12, r2[10]@23, r3[9]@33
    __shared__ float Xs[64][132];
    const int tid = threadIdx.x;
    const int wave = tid >> 6, lane = tid & 63;
    const int m = lane & 15, q = lane >> 4;
    const int r0 = blockIdx.x * 64;

    if (tid < 128) {
        float t[12];
#pragma unroll
        for (int j = 0; j < 12; j++) t[j] = grid[tid * 12 + j];
#pragma unroll
        for (int j = 0; j < 12; j++) RD[tid][j] = t[j];
#pragma unroll
        for (int mm = 0; mm < 11; mm++) RD[tid][12 + mm] = 1.f / (t[mm + 1] - t[mm]);
#pragma unroll
        for (int mm = 0; mm < 10; mm++) RD[tid][23 + mm] = 1.f / (t[mm + 2] - t[mm]);
#pragma unroll
        for (int mm = 0; mm < 9; mm++) RD[tid][33 + mm] = 1.f / (t[mm + 3] - t[mm]);
    }
    {   // stage 64x128 X tile
        const int row = tid >> 2, cq = (tid & 3) * 32;
        const float* p = &X[(size_t)(r0 + row) * 128 + cq];
#pragma unroll
        for (int v = 0; v < 8; v++) *(float4*)&Xs[row][cq + v * 4] = *(const float4*)(p + v * 4);
    }
    __syncthreads();

    const int rowl = wave * 16 + m;
    f32x4 acc[4] = {};

    // phase A: silu(x) @ base1^T (K=128), split-bf16 A, exact-bf16 W
#pragma unroll
    for (int kt = 0; kt < 4; kt++) {
        float xv[8];
        *(float4*)&xv[0] = *(const float4*)&Xs[rowl][kt * 32 + q * 8];
        *(float4*)&xv[4] = *(const float4*)&Xs[rowl][kt * 32 + q * 8 + 4];
        short8 ah, al;
#pragma unroll
        for (int j = 0; j < 8; j++) {
            float x = xv[j];
            float s = x / (1.f + __expf(-x));
            unsigned short hi, lo;
            split2(s, hi, lo);
            ((unsigned short*)&ah)[j] = hi;
            ((unsigned short*)&al)[j] = lo;
        }
#pragma unroll
        for (int nt = 0; nt < 4; nt++) {
            short8 b = *(const short8*)(basef + (((size_t)(kt * 4 + nt) * 64 + lane) << 3));
            acc[nt] = __builtin_amdgcn_mfma_f32_16x16x32_bf16(ah, b, acc[nt], 0, 0, 0);
            acc[nt] = __builtin_amdgcn_mfma_f32_16x16x32_bf16(al, b, acc[nt], 0, 0, 0);
        }
    }

    // phase B: spline GEMM (K=1024), feature i = kt*4+q; split bases x split weights
#pragma unroll 1
    for (int kt = 0; kt < 32; kt++) {
        const int i = kt * 4 + q;
        float x = Xs[rowl][i];
        float b8[8];
        bases8(x, &RD[i][0], &RD[i][12], &RD[i][23], &RD[i][33], b8);
        short8 bh, bl;
#pragma unroll
        for (int j = 0; j < 8; j++) {
            unsigned short hi, lo;
            split2(b8[j], hi, lo);
            ((unsigned short*)&bh)[j] = hi;
            ((unsigned short*)&bl)[j] = lo;
        }
#pragma unroll
        for (int nt = 0; nt < 4; nt++) {
            const size_t idx = ((size_t)(kt * 4 + nt) * 64 + lane) << 3;
            short8 wh = *(const short8*)(swh + idx);
            short8 wl = *(const short8*)(swl + idx);
            acc[nt] = __builtin_amdgcn_mfma_f32_16x16x32_bf16(bh, wh, acc[nt], 0, 0, 0);
            acc[nt] = __builtin_amdgcn_mfma_f32_16x16x32_bf16(bl, wh, acc[nt], 0, 0, 0);
            acc[nt] = __builtin_amdgcn_mfma_f32_16x16x32_bf16(bh, wl, acc[nt], 0, 0, 0);
        }
    }

#pragma unroll
    for (int r = 0; r < 4; r++) {
        int grow = r0 + wave * 16 + q * 4 + r;  // C layout: col=lane&15, row=(lane>>4)*4+reg
#pragma unroll
        for (int nt = 0; nt < 4; nt++) Hout[(size_t)grow * 64 + nt * 16 + m] = acc[nt][r];
    }
}

// ---------------- KAN layer 2 (round-2 known-good) ----------------
__global__ __launch_bounds__(256) void kan2_kernel(const float* __restrict__ h, const float* __restrict__ base2,
                                                   const float* __restrict__ sw2, const float* __restrict__ grid2,
                                                   void* __restrict__ out, const int* __restrict__ flag) {
    const int lane = threadIdx.x & 63;
    const int wid = (blockIdx.x * blockDim.x + threadIdx.x) >> 6;
    const int nw = (gridDim.x * blockDim.x) >> 6;
    const int k = lane;
    float t[12];
#pragma unroll
    for (int j = 0; j < 12; j++) t[j] = grid2[k * 12 + j];
    float r1[11], r2[10], r3[9];
#pragma unroll
    for (int m = 0; m < 11; m++) r1[m] = 1.f / (t[m + 1] - t[m]);
#pragma unroll
    for (int m = 0; m < 10; m++) r2[m] = 1.f / (t[m + 2] - t[m]);
#pragma unroll
    for (int m = 0; m < 9; m++) r3[m] = 1.f / (t[m + 3] - t[m]);
    const float wb0 = base2[k], wb1 = base2[64 + k];
    float ws0[8], ws1[8];
#pragma unroll
    for (int j = 0; j < 8; j++) { ws0[j] = sw2[k * 8 + j]; ws1[j] = sw2[512 + k * 8 + j]; }
    const int isbf = *flag;

    for (int n = wid; n < kNE; n += nw) {
        float x = h[(size_t)n * 64 + k];
        float sil = x / (1.f + __expf(-x));
        float b[8];
        bases8(x, t, r1, r2, r3, b);
        float o0 = sil * wb0, o1 = sil * wb1;
#pragma unroll
        for (int j = 0; j < 8; j++) {
            o0 = fmaf(b[j], ws0[j], o0);
            o1 = fmaf(b[j], ws1[j], o1);
        }
#pragma unroll
        for (int off = 32; off > 0; off >>= 1) {
            o0 += __shfl_down(o0, off, 64);
            o1 += __shfl_down(o1, off, 64);
        }
        if (lane == 0) {
            if (isbf) {
                __hip_bfloat16* ob = (__hip_bfloat16*)out;
                ob[(size_t)n * 2] = __float2bfloat16(o0);
                ob[(size_t)n * 2 + 1] = __float2bfloat16(o1);
            } else {
                ((float2*)out)[n] = make_float2(o0, o1);
            }
        }
    }
}

// ---------------- launch ----------------
extern "C" void kernel_launch(void* const* d_in, const int* in_sizes, int n_in, void* d_out, int out_size,
                              void* d_ws, size_t ws_size, hipStream_t stream) {
    (void)in_sizes; (void)n_in; (void)out_size; (void)ws_size;
    float* wsf = (float*)d_ws;
    int* wsi = (int*)d_ws;
    unsigned short* fbase = (unsigned short*)(wsi + FR_BASE_I);

    zero_kernel<<<(kNE + kNU + 255) / 256, 256, 0, stream>>>(wsi + I_CNT_UE, kNE + kNU);
    detect_kernel<<<1, 64, 0, stream>>>((const unsigned int*)d_in[21], wsi + O_FLAG);

    // small fp32 converts: lin weights + biases + grids + kan2 base
    ConvJobs jobs;
    const int srcIdx[14] = {3, 4, 6, 7, 8, 9, 10, 11, 12, 13, 14, 21, 22, 25};
    const long long dstOff[14] = {O_WEM, O_BEM, O_W1N, O_BL1, O_W1R, O_WEN, O_BEN, O_WER,
                                  O_W2N, O_BL2, O_W2R, O_GRID1, O_BASE2, O_GRID2};
    const int cnts[14] = {8192, 128, 16384, 128, 16384, 16384, 128, 16384, 16384, 128, 16384, 1536, 128, 768};
    for (int t = 0; t < 14; t++) {
        jobs.src[t] = d_in[srcIdx[t]];
        jobs.off[t] = (int)dstOff[t];
        jobs.n[t] = cnts[t];
    }
    convert_jobs_kernel<<<64, 256, 0, stream>>>(jobs, wsf, wsi + O_FLAG);
    premult_kernel<<<4, 256, 0, stream>>>(d_in[23], d_in[24], wsf + O_SW2, 1024, wsi + O_FLAG);
    frag_base1_kernel<<<4, 256, 0, stream>>>(d_in[18], fbase + U_BASE1, wsi + O_FLAG);
    frag_sw1_kernel<<<32, 256, 0, stream>>>(d_in[19], d_in[20], fbase + U_SW1H, fbase + U_SW1L, wsi + O_FLAG);

    const int* ei_ue = (const int*)d_in[1];
    const int* ei_eu = (const int*)d_in[2];
    const int egrid = (kE + 255) / 256;

    // CSR build
    hist_kernel<<<egrid, 256, 0, stream>>>(ei_ue + kE, wsi + I_CNT_UE, kE);
    hist_kernel<<<egrid, 256, 0, stream>>>(ei_eu + kE, wsi + I_CNT_EU, kE);
    scan1_kernel<<<196, 256, 0, stream>>>(wsi + I_CNT_UE, wsi + I_RO_UE, wsi + I_BSUM_UE, kNE);
    scan2_kernel<<<1, 256, 0, stream>>>(wsi + I_BSUM_UE, wsi + I_BOFF_UE, 196);
    scan3_kernel<<<512, 256, 0, stream>>>(wsi + I_RO_UE, wsi + I_CUR_UE, wsi + I_BOFF_UE, kNE);
    scan1_kernel<<<98, 256, 0, stream>>>(wsi + I_CNT_EU, wsi + I_RO_EU, wsi + I_BSUM_EU, kNU);
    scan2_kernel<<<1, 256, 0, stream>>>(wsi + I_BSUM_EU, wsi + I_BOFF_EU, 98);
    scan3_kernel<<<512, 256, 0, stream>>>(wsi + I_RO_EU, wsi + I_CUR_EU, wsi + I_BOFF_EU, kNU);
    fill_kernel<<<egrid, 256, 0, stream>>>(ei_ue, ei_ue + kE, wsi + I_CUR_UE, wsi + I_SRT_UE, kE);
    fill_kernel<<<egrid, 256, 0, stream>>>(ei_eu, ei_eu + kE, wsi + I_CUR_EU, wsi + I_SRT_EU, kE);

    // 1. xe = x_email @ w_email^T + b_email -> B0
    lin_kernel<64, true, false, false, false><<<3125, 256, 0, stream>>>(
        d_in[0], nullptr, wsf + O_WEM, nullptr, wsf + O_BEM, wsf + O_B0, kNE, wsi + O_FLAG);

    // 2. mean_ue1 -> B1;  3. e1 = relu(lin(B1)+lin(xe)) -> B1
    agg_kernel<true><<<kNE / 4, 256, 0, stream>>>(d_in[5], wsf + O_B1, wsi + I_RO_UE, wsi + I_CNT_UE,
                                                  wsi + I_SRT_UE, kNE, wsi + O_FLAG);
    lin_kernel<128, false, false, true, true><<<3125, 256, 0, stream>>>(
        wsf + O_B1, wsf + O_B0, wsf + O_W1N, wsf + O_W1R, wsf + O_BL1, wsf + O_B1, kNE, wsi + O_FLAG);

    // 4. mean_eu -> B2;  5. u1 = relu(lin(B2)+lin(emb)) -> B2.  B0 free.
    agg_kernel<false><<<kNU / 4, 256, 0, stream>>>(wsf + O_B0, wsf + O_B2, wsi + I_RO_EU, wsi + I_CNT_EU,
                                                   wsi + I_SRT_EU, kNU, wsi + O_FLAG);
    lin_kernel<128, false, true, true, true><<<1563, 256, 0, stream>>>(
        wsf + O_B2, d_in[5], wsf + O_WEN, wsf + O_WER, wsf + O_BEN, wsf + O_B2, kNU, wsi + O_FLAG);

    // 6. mean_ue2 -> B0;  7. e2 = relu(lin(B0)+lin(e1)) -> B0.  B1 free.
    agg_kernel<false><<<kNE / 4, 256, 0, stream>>>(wsf + O_B2, wsf + O_B0, wsi + I_RO_UE, wsi + I_CNT_UE,
                                                   wsi + I_SRT_UE, kNE, wsi + O_FLAG);
    lin_kernel<128, false, false, true, true><<<3125, 256, 0, stream>>>(
        wsf + O_B0, wsf + O_B1, wsf + O_W2N, wsf + O_W2R, wsf + O_BL2, wsf + O_B0, kNE, wsi + O_FLAG);

    // 8. h = kan1_mfma(e2) -> B1;  9. out = kan2(h)
    kan1_mfma<<<3125, 256, 0, stream>>>(wsf + O_B0, fbase + U_BASE1, fbase + U_SW1H, fbase + U_SW1L,
                                        wsf + O_GRID1, wsf + O_B1);
    kan2_kernel<<<2048, 256, 0, stream>>>(wsf + O_B1, wsf + O_BASE2, wsf + O_SW2, wsf + O_GRID2, d_out,
                                          wsi + O_FLAG);
}

// Round 8
// 1557.360 us; speedup vs baseline: 1.3437x; 1.0597x over previous
//
#include <hip/hip_runtime.h>
#include <hip/hip_bf16.h>

typedef __attribute__((ext_vector_type(8))) short short8;
typedef __attribute__((ext_vector_type(4))) float f32x4;

// ---------------- problem constants ----------------
static constexpr int kNE  = 200000;   // emails
static constexpr int kNU  = 100000;   // users
static constexpr int kE   = 1000000;  // edges per type

// ---------------- workspace layout (4-byte element offsets) ----------------
// HARD CONSTRAINT (r5, reconfirmed r7): ws_size = 256 MiB = 268,435,456 B.
// Verified arithmetic (r8): FR_BASE_I = 66,905,056 ints = 267,620,224 B; frag region
// 245,760 ushorts = 491,520 B; END = 268,111,744 B; margin = 323,712 B.
static constexpr long long O_FLAG = 0;                     // int flag (64 reserved)
static constexpr long long SZ_NEH = (long long)kNE * 128;  // 25.6M
static constexpr long long SZ_NUH = (long long)kNU * 128;  // 12.8M
static constexpr long long O_B0   = 64;
static constexpr long long O_B1   = O_B0 + SZ_NEH;
static constexpr long long O_B2   = O_B1 + SZ_NEH;
static constexpr long long O_W    = O_B2 + SZ_NUH;         // 64,000,064
static constexpr long long O_BEM  = O_W;                   // 128
static constexpr long long O_BL1  = O_BEM + 128;           // 128
static constexpr long long O_BEN  = O_BL1 + 128;           // 128
static constexpr long long O_BL2  = O_BEN + 128;           // 128
static constexpr long long O_GRID1= O_BL2 + 128;           // 1536
static constexpr long long O_BASE2= O_GRID1 + 1536;        // 128
static constexpr long long O_GRID2= O_BASE2 + 128;         // 768
static constexpr long long O_SW2  = O_GRID2 + 768;         // 1024
// int region
static constexpr long long I_CNT_UE = O_SW2 + 1024;        // 64,004,032; cnt_ue,cnt_eu contiguous
static constexpr long long I_CNT_EU = I_CNT_UE + kNE;
static constexpr long long I_RO_UE  = I_CNT_EU + kNU;
static constexpr long long I_RO_EU  = I_RO_UE + kNE;
static constexpr long long I_CUR_UE = I_RO_EU + kNU;
static constexpr long long I_CUR_EU = I_CUR_UE + kNE;
static constexpr long long I_SRT_UE = I_CUR_EU + kNU;
static constexpr long long I_SRT_EU = I_SRT_UE + kE;
static constexpr long long I_BSUM_UE= I_SRT_EU + kE;
static constexpr long long I_BOFF_UE= I_BSUM_UE + 256;
static constexpr long long I_BSUM_EU= I_BOFF_UE + 256;
static constexpr long long I_BOFF_EU= I_BSUM_EU + 256;
static constexpr long long FR_BASE_I= (I_BOFF_EU + 256 + 7) & ~7LL;  // = 66,905,056
// bf16 MFMA B-fragment region (ushort offsets from fbase); total 245,760 ushorts
static constexpr long long U_WEM   = 0;                  // [128][64]
static constexpr long long U_W1N   = U_WEM + 8192;       // [128][128]
static constexpr long long U_W1R   = U_W1N + 16384;
static constexpr long long U_WEN   = U_W1R + 16384;
static constexpr long long U_WER   = U_WEN + 16384;
static constexpr long long U_W2N   = U_WER + 16384;
static constexpr long long U_W2R   = U_W2N + 16384;
static constexpr long long U_BASE1 = U_W2R + 16384;      // [64][128]
static constexpr long long U_SW1H  = U_BASE1 + 8192;     // [64][1024] hi
static constexpr long long U_SW1L  = U_SW1H + 65536;     // lo

__device__ __forceinline__ float bf2f(unsigned short u) {
    return __uint_as_float(((unsigned)u) << 16);
}
__device__ __forceinline__ unsigned short f2bf_rne(float f) {
    unsigned u = __float_as_uint(f);
    return (unsigned short)((u + 0x7fffu + ((u >> 16) & 1u)) >> 16);
}
__device__ __forceinline__ void split2(float x, unsigned short& hi, unsigned short& lo) {
    hi = f2bf_rne(x);
    lo = f2bf_rne(x - bf2f(hi));
}

// ---------------- dtype detection ----------------
__global__ void detect_kernel(const unsigned int* __restrict__ g, int* __restrict__ flag) {
    if (threadIdx.x == 0 && blockIdx.x == 0)
        flag[0] = (g[0] == 0xC00CCCCDu) ? 0 : 1;
}

__global__ __launch_bounds__(256) void zero_kernel(int* __restrict__ p, int n) {
    int i = blockIdx.x * 256 + threadIdx.x;
    if (i < n) p[i] = 0;
}

// ---------------- converts (biases + grids + kan2 base only) ----------------
struct ConvJobs {
    const void* src[7];
    int off[7];
    int n[7];
};

__global__ __launch_bounds__(256) void convert_jobs_kernel(ConvJobs jobs, float* __restrict__ wsf,
                                                           const int* __restrict__ flag) {
    const int isbf = *flag;
    const int stride = gridDim.x * blockDim.x;
    const int t0 = blockIdx.x * blockDim.x + threadIdx.x;
    for (int t = 0; t < 7; t++) {
        const int n = jobs.n[t];
        const void* s = jobs.src[t];
        float* d = wsf + jobs.off[t];
        for (int i = t0; i < n; i += stride)
            d[i] = isbf ? bf2f(((const unsigned short*)s)[i]) : ((const float*)s)[i];
    }
}

// sw2[o][i][j] = spline_w[o][i][j] * scaler[o][i]  (fp32, for kan2)
__global__ __launch_bounds__(256) void premult_kernel(const void* __restrict__ sp, const void* __restrict__ sc,
                                                      float* __restrict__ dst, int n, const int* __restrict__ flag) {
    const int isbf = *flag;
    const int stride = gridDim.x * blockDim.x;
    for (int i = blockIdx.x * blockDim.x + threadIdx.x; i < n; i += stride) {
        float a = isbf ? bf2f(((const unsigned short*)sp)[i]) : ((const float*)sp)[i];
        float b = isbf ? bf2f(((const unsigned short*)sc)[i >> 3]) : ((const float*)sc)[i >> 3];
        dst[i] = a * b;
    }
}

// ---------------- B-fragment pack, parameterized clone of the VERIFIED frag_base1_kernel ----------
// frag element: dst[((kt*NT + nt)*64 + lane)*8 + j] = W[nt*16 + (lane&15)][kt*32 + (lane>>4)*8 + j]
template <int O, int K>
__global__ __launch_bounds__(256) void pack_frag(const void* __restrict__ src,
                                                 unsigned short* __restrict__ dst,
                                                 const int* __restrict__ flag) {
    constexpr int NT = O / 16, KT = K / 32, TOT = KT * NT * 64;
    const int t = blockIdx.x * 256 + threadIdx.x;
    if (t >= TOT) return;
    const int isbf = *flag;
    const int lane = t & 63;
    const int nt = (t >> 6) % NT;
    const int kt = (t >> 6) / NT;
    const int n = nt * 16 + (lane & 15);
    const int k0 = kt * 32 + (lane >> 4) * 8;
    unsigned short* d = dst + (((size_t)(kt * NT + nt) * 64 + lane) << 3);
#pragma unroll
    for (int j = 0; j < 8; j++) {
        float f = isbf ? bf2f(((const unsigned short*)src)[(size_t)n * K + k0 + j])
                       : ((const float*)src)[(size_t)n * K + k0 + j];
        d[j] = f2bf_rne(f);  // exact when storage is bf16
    }
}

// ---------------- kan1 packs (verified round 6, unchanged) ----------------
__global__ __launch_bounds__(256) void frag_base1_kernel(const void* __restrict__ src,
                                                         unsigned short* __restrict__ dst,
                                                         const int* __restrict__ flag) {
    const int t = blockIdx.x * 256 + threadIdx.x;  // 4*4*64 = 1024
    if (t >= 1024) return;
    const int isbf = *flag;
    const int lane = t & 63, nt = (t >> 6) & 3, kt = t >> 8;
    const int n = nt * 16 + (lane & 15);
    const int k0 = kt * 32 + (lane >> 4) * 8;
    unsigned short* d = dst + (((size_t)(kt * 4 + nt) * 64 + lane) << 3);
#pragma unroll
    for (int j = 0; j < 8; j++) {
        float f = isbf ? bf2f(((const unsigned short*)src)[n * 128 + k0 + j])
                       : ((const float*)src)[n * 128 + k0 + j];
        d[j] = f2bf_rne(f);
    }
}

__global__ __launch_bounds__(256) void frag_sw1_kernel(const void* __restrict__ sp, const void* __restrict__ sc,
                                                       unsigned short* __restrict__ dh,
                                                       unsigned short* __restrict__ dl,
                                                       const int* __restrict__ flag) {
    const int t = blockIdx.x * 256 + threadIdx.x;  // 32*4*64 = 8192
    if (t >= 8192) return;
    const int isbf = *flag;
    const int lane = t & 63, nt = (t >> 6) & 3, kt = t >> 8;
    const int n = nt * 16 + (lane & 15);
    const int k0 = kt * 32 + (lane >> 4) * 8;
    const float scal = isbf ? bf2f(((const unsigned short*)sc)[n * 128 + (k0 >> 3)])
                            : ((const float*)sc)[n * 128 + (k0 >> 3)];
    const size_t base = ((size_t)(kt * 4 + nt) * 64 + lane) << 3;
#pragma unroll
    for (int j = 0; j < 8; j++) {
        float f = isbf ? bf2f(((const unsigned short*)sp)[(size_t)n * 1024 + k0 + j])
                       : ((const float*)sp)[(size_t)n * 1024 + k0 + j];
        float p = f * scal;
        unsigned short hi, lo;
        split2(p, hi, lo);
        dh[base + j] = hi;
        dl[base + j] = lo;
    }
}

// ---------------- CSR build ----------------
__global__ __launch_bounds__(256) void hist_kernel(const int* __restrict__ dst, int* __restrict__ cnt, int n) {
    int i = blockIdx.x * 256 + threadIdx.x;
    if (i < n) atomicAdd(&cnt[dst[i]], 1);
}

__global__ __launch_bounds__(256) void scan1_kernel(const int* __restrict__ cnt, int* __restrict__ ro,
                                                    int* __restrict__ bsum, int n) {
    __shared__ int sc[256];
    const int t = threadIdx.x;
    const int i0 = blockIdx.x * 1024 + t * 4;
    int c[4];
#pragma unroll
    for (int q = 0; q < 4; q++) c[q] = (i0 + q < n) ? cnt[i0 + q] : 0;
    int s = c[0] + c[1] + c[2] + c[3];
    sc[t] = s;
    __syncthreads();
    for (int off = 1; off < 256; off <<= 1) {
        int v = (t >= off) ? sc[t - off] : 0;
        __syncthreads();
        sc[t] += v;
        __syncthreads();
    }
    int run = sc[t] - s;  // exclusive
#pragma unroll
    for (int q = 0; q < 4; q++) {
        if (i0 + q < n) ro[i0 + q] = run;
        run += c[q];
    }
    if (t == 255) bsum[blockIdx.x] = sc[255];
}

__global__ __launch_bounds__(256) void scan2_kernel(const int* __restrict__ bsum, int* __restrict__ boff, int nb) {
    __shared__ int sc[256];
    const int t = threadIdx.x;
    int s = (t < nb) ? bsum[t] : 0;
    sc[t] = s;
    __syncthreads();
    for (int off = 1; off < 256; off <<= 1) {
        int v = (t >= off) ? sc[t - off] : 0;
        __syncthreads();
        sc[t] += v;
        __syncthreads();
    }
    if (t < nb) boff[t] = sc[t] - s;
}

__global__ __launch_bounds__(256) void scan3_kernel(int* __restrict__ ro, int* __restrict__ cur,
                                                    const int* __restrict__ boff, int n) {
    const int stride = gridDim.x * blockDim.x;
    for (int i = blockIdx.x * blockDim.x + threadIdx.x; i < n; i += stride) {
        int v = ro[i] + boff[i >> 10];
        ro[i] = v;
        cur[i] = v;
    }
}

__global__ __launch_bounds__(256) void fill_kernel(const int* __restrict__ src, const int* __restrict__ dst,
                                                   int* __restrict__ cur, int* __restrict__ sorted, int n) {
    int i = blockIdx.x * 256 + threadIdx.x;
    if (i < n) {
        int pos = atomicAdd(&cur[dst[i]], 1);
        sorted[pos] = src[i];
    }
}

// ---------------- segment mean (wave per dst row) ----------------
template <bool RAWSRC>
__global__ __launch_bounds__(256) void agg_kernel(const void* __restrict__ srcv, float* __restrict__ mean,
                                                  const int* __restrict__ ro, const int* __restrict__ cnt,
                                                  const int* __restrict__ sorted, int Ndst,
                                                  const int* __restrict__ flag) {
    const int lane = threadIdx.x & 63;
    const int n = (blockIdx.x << 2) + (threadIdx.x >> 6);
    if (n >= Ndst) return;
    const int isbf = RAWSRC ? *flag : 0;
    const int beg = ro[n];
    const int deg = cnt[n];
    float ax = 0.f, ay = 0.f;
    for (int p = beg; p < beg + deg; p++) {
        int s = sorted[p];
        if (RAWSRC && isbf) {
            const ushort2 v = *(const ushort2*)((const unsigned short*)srcv + (size_t)s * 128 + lane * 2);
            ax += bf2f(v.x);
            ay += bf2f(v.y);
        } else {
            const float2 v = *(const float2*)((const float*)srcv + (size_t)s * 128 + lane * 2);
            ax += v.x;
            ay += v.y;
        }
    }
    const float inv = (deg > 0) ? 1.f / (float)deg : 0.f;
    *(float2*)&mean[(size_t)n * 128 + lane * 2] = make_float2(ax * inv, ay * inv);
}

// ---------------- LDS tile staging (kan1-verified pattern, + row clamp + bf16 source) ----------------
template <int KD, bool RAW>
__device__ __forceinline__ void stage_tile(float (*Xs)[132], const void* __restrict__ Av, int r0, int N,
                                           int tid, int isbf) {
    const int row = tid >> 2;
    constexpr int per = KD / 4;            // 16 (KD=64) or 32 (KD=128) elems per thread
    const int cq = (tid & 3) * per;
    const size_t gr = (size_t)min(r0 + row, N - 1);  // clamp: tail-safe, outputs guarded later
    if (RAW && isbf) {
        const unsigned short* p = (const unsigned short*)Av + gr * KD + cq;
#pragma unroll
        for (int v = 0; v < per; v += 8) {
            short8 s = *(const short8*)(p + v);
#pragma unroll
            for (int j = 0; j < 8; j++) Xs[row][cq + v + j] = bf2f(((unsigned short*)&s)[j]);
        }
    } else {
        const float* p = (const float*)Av + gr * KD + cq;
#pragma unroll
        for (int v = 0; v < per; v += 4) *(float4*)&Xs[row][cq + v] = *(const float4*)(p + v);
    }
}

// ---------------- MFMA (dual-)GEMM, minimal-delta clone of VERIFIED kan1_mfma ----------------
// out = [relu]( A1@W1^T [+ A2@W2^T] + bias ), O=128. A staged via LDS (kan1 pattern), split-bf16
// hi/lo A (kan1 phase-A pattern), exact-bf16 W frags (pack_frag). In-place out==A1 safe: block
// reads only rows [r0,r0+64) and writes them only in the epilogue.
template <int KD1, bool RAW1, bool RAW2, bool HASA2, bool RELU>
__global__ __launch_bounds__(256) void lin_mfma(const void* __restrict__ A1, const void* __restrict__ A2,
                                                const unsigned short* __restrict__ W1f,
                                                const unsigned short* __restrict__ W2f,
                                                const float* __restrict__ bias, float* __restrict__ out, int N,
                                                const int* __restrict__ flag) {
    __shared__ float Xs[64][132];
    const int tid = threadIdx.x;
    const int wave = tid >> 6, lane = tid & 63;
    const int m = lane & 15, q = lane >> 4;
    const int r0 = blockIdx.x * 64;
    const int isbf = *flag;
    const int rowl = wave * 16 + m;
    f32x4 acc[8] = {};

    // phase 1: A1 @ W1^T
    stage_tile<KD1, RAW1>(Xs, A1, r0, N, tid, isbf);
    __syncthreads();
#pragma unroll
    for (int kt = 0; kt < KD1 / 32; kt++) {
        float xv[8];
        *(float4*)&xv[0] = *(const float4*)&Xs[rowl][kt * 32 + q * 8];
        *(float4*)&xv[4] = *(const float4*)&Xs[rowl][kt * 32 + q * 8 + 4];
        short8 ah, al;
#pragma unroll
        for (int j = 0; j < 8; j++) {
            unsigned short hi, lo;
            split2(xv[j], hi, lo);
            ((unsigned short*)&ah)[j] = hi;
            ((unsigned short*)&al)[j] = lo;
        }
#pragma unroll
        for (int nt = 0; nt < 8; nt++) {
            short8 b = *(const short8*)(W1f + (((size_t)(kt * 8 + nt) * 64 + lane) << 3));
            acc[nt] = __builtin_amdgcn_mfma_f32_16x16x32_bf16(ah, b, acc[nt], 0, 0, 0);
            acc[nt] = __builtin_amdgcn_mfma_f32_16x16x32_bf16(al, b, acc[nt], 0, 0, 0);
        }
    }

    // phase 2: + A2 @ W2^T (KD=128)
    if (HASA2) {
        __syncthreads();
        stage_tile<128, RAW2>(Xs, A2, r0, N, tid, isbf);
        __syncthreads();
#pragma unroll
        for (int kt = 0; kt < 4; kt++) {
            float xv[8];
            *(float4*)&xv[0] = *(const float4*)&Xs[rowl][kt * 32 + q * 8];
            *(float4*)&xv[4] = *(const float4*)&Xs[rowl][kt * 32 + q * 8 + 4];
            short8 ah, al;
#pragma unroll
            for (int j = 0; j < 8; j++) {
                unsigned short hi, lo;
                split2(xv[j], hi, lo);
                ((unsigned short*)&ah)[j] = hi;
                ((unsigned short*)&al)[j] = lo;
            }
#pragma unroll
            for (int nt = 0; nt < 8; nt++) {
                short8 b = *(const short8*)(W2f + (((size_t)(kt * 8 + nt) * 64 + lane) << 3));
                acc[nt] = __builtin_amdgcn_mfma_f32_16x16x32_bf16(ah, b, acc[nt], 0, 0, 0);
                acc[nt] = __builtin_amdgcn_mfma_f32_16x16x32_bf16(al, b, acc[nt], 0, 0, 0);
            }
        }
    }

    // epilogue (kan1-verified C layout: row=(lane>>4)*4+reg, col=lane&15) + bias + relu
    float bv[8];
#pragma unroll
    for (int nt = 0; nt < 8; nt++) bv[nt] = bias[nt * 16 + m];
#pragma unroll
    for (int r = 0; r < 4; r++) {
        int grow = r0 + wave * 16 + q * 4 + r;
        if (grow < N) {
#pragma unroll
            for (int nt = 0; nt < 8; nt++) {
                float v = acc[nt][r] + bv[nt];
                out[(size_t)grow * 128 + nt * 16 + m] = RELU ? fmaxf(v, 0.f) : v;
            }
        }
    }
}

// ---------------- Cox-de Boor, compact reciprocals (verified) ----------------
__device__ __forceinline__ void bases8(float x, const float* __restrict__ t, const float* __restrict__ r1,
                                       const float* __restrict__ r2, const float* __restrict__ r3,
                                       float* __restrict__ b) {
    float bb[11];
#pragma unroll
    for (int m = 0; m < 11; m++) bb[m] = (x >= t[m] && x < t[m + 1]) ? 1.f : 0.f;
#pragma unroll
    for (int m = 0; m < 10; m++) bb[m] = (x - t[m]) * r1[m] * bb[m] + (t[m + 2] - x) * r1[m + 1] * bb[m + 1];
#pragma unroll
    for (int m = 0; m < 9; m++) bb[m] = (x - t[m]) * r2[m] * bb[m] + (t[m + 3] - x) * r2[m + 1] * bb[m + 1];
#pragma unroll
    for (int m = 0; m < 8; m++) b[m] = (x - t[m]) * r3[m] * bb[m] + (t[m + 4] - x) * r3[m + 1] * bb[m + 1];
}

// ---------------- KAN layer 1 (verified round 6, unchanged) ----------------
__global__ __launch_bounds__(256) void kan1_mfma(const float* __restrict__ X,
                                                 const unsigned short* __restrict__ basef,
                                                 const unsigned short* __restrict__ swh,
                                                 const unsigned short* __restrict__ swl,
                                                 const float* __restrict__ grid, float* __restrict__ Hout) {
    __shared__ float RD[128][42];  // t[12]@0, r1[11]@12, r2[10]@23, r3[9]@33
    __shared__ float Xs[64][132];
    const int tid = threadIdx.x;
    const int wave = tid >> 6, lane = tid & 63;
    const int m = lane & 15, q = lane >> 4;
    const int r0 = blockIdx.x * 64;

    if (tid < 128) {
        float t[12];
#pragma unroll
        for (int j = 0; j < 12; j++) t[j] = grid[tid * 12 + j];
#pragma unroll
        for (int j = 0; j < 12; j++) RD[tid][j] = t[j];
#pragma unroll
        for (int mm = 0; mm < 11; mm++) RD[tid][12 + mm] = 1.f / (t[mm + 1] - t[mm]);
#pragma unroll
        for (int mm = 0; mm < 10; mm++) RD[tid][23 + mm] = 1.f / (t[mm + 2] - t[mm]);
#pragma unroll
        for (int mm = 0; mm < 9; mm++) RD[tid][33 + mm] = 1.f / (t[mm + 3] - t[mm]);
    }
    {   // stage 64x128 X tile
        const int row = tid >> 2, cq = (tid & 3) * 32;
        const float* p = &X[(size_t)(r0 + row) * 128 + cq];
#pragma unroll
        for (int v = 0; v < 8; v++) *(float4*)&Xs[row][cq + v * 4] = *(const float4*)(p + v * 4);
    }
    __syncthreads();

    const int rowl = wave * 16 + m;
    f32x4 acc[4] = {};

    // phase A: silu(x) @ base1^T (K=128), split-bf16 A, exact-bf16 W
#pragma unroll
    for (int kt = 0; kt < 4; kt++) {
        float xv[8];
        *(float4*)&xv[0] = *(const float4*)&Xs[rowl][kt * 32 + q * 8];
        *(float4*)&xv[4] = *(const float4*)&Xs[rowl][kt * 32 + q * 8 + 4];
        short8 ah, al;
#pragma unroll
        for (int j = 0; j < 8; j++) {
            float x = xv[j];
            float s = x / (1.f + __expf(-x));
            unsigned short hi, lo;
            split2(s, hi, lo);
            ((unsigned short*)&ah)[j] = hi;
            ((unsigned short*)&al)[j] = lo;
        }
#pragma unroll
        for (int nt = 0; nt < 4; nt++) {
            short8 b = *(const short8*)(basef + (((size_t)(kt * 4 + nt) * 64 + lane) << 3));
            acc[nt] = __builtin_amdgcn_mfma_f32_16x16x32_bf16(ah, b, acc[nt], 0, 0, 0);
            acc[nt] = __builtin_amdgcn_mfma_f32_16x16x32_bf16(al, b, acc[nt], 0, 0, 0);
        }
    }

    // phase B: spline GEMM (K=1024), feature i = kt*4+q; split bases x split weights
#pragma unroll 1
    for (int kt = 0; kt < 32; kt++) {
        const int i = kt * 4 + q;
        float x = Xs[rowl][i];
        float b8[8];
        bases8(x, &RD[i][0], &RD[i][12], &RD[i][23], &RD[i][33], b8);
        short8 bh, bl;
#pragma unroll
        for (int j = 0; j < 8; j++) {
            unsigned short hi, lo;
            split2(b8[j], hi, lo);
            ((unsigned short*)&bh)[j] = hi;
            ((unsigned short*)&bl)[j] = lo;
        }
#pragma unroll
        for (int nt = 0; nt < 4; nt++) {
            const size_t idx = ((size_t)(kt * 4 + nt) * 64 + lane) << 3;
            short8 wh = *(const short8*)(swh + idx);
            short8 wl = *(const short8*)(swl + idx);
            acc[nt] = __builtin_amdgcn_mfma_f32_16x16x32_bf16(bh, wh, acc[nt], 0, 0, 0);
            acc[nt] = __builtin_amdgcn_mfma_f32_16x16x32_bf16(bl, wh, acc[nt], 0, 0, 0);
            acc[nt] = __builtin_amdgcn_mfma_f32_16x16x32_bf16(bh, wl, acc[nt], 0, 0, 0);
        }
    }

#pragma unroll
    for (int r = 0; r < 4; r++) {
        int grow = r0 + wave * 16 + q * 4 + r;
#pragma unroll
        for (int nt = 0; nt < 4; nt++) Hout[(size_t)grow * 64 + nt * 16 + m] = acc[nt][r];
    }
}

// ---------------- KAN layer 2 (verified, unchanged) ----------------
__global__ __launch_bounds__(256) void kan2_kernel(const float* __restrict__ h, const float* __restrict__ base2,
                                                   const float* __restrict__ sw2, const float* __restrict__ grid2,
                                                   void* __restrict__ out, const int* __restrict__ flag) {
    const int lane = threadIdx.x & 63;
    const int wid = (blockIdx.x * blockDim.x + threadIdx.x) >> 6;
    const int nw = (gridDim.x * blockDim.x) >> 6;
    const int k = lane;
    float t[12];
#pragma unroll
    for (int j = 0; j < 12; j++) t[j] = grid2[k * 12 + j];
    float r1[11], r2[10], r3[9];
#pragma unroll
    for (int m = 0; m < 11; m++) r1[m] = 1.f / (t[m + 1] - t[m]);
#pragma unroll
    for (int m = 0; m < 10; m++) r2[m] = 1.f / (t[m + 2] - t[m]);
#pragma unroll
    for (int m = 0; m < 9; m++) r3[m] = 1.f / (t[m + 3] - t[m]);
    const float wb0 = base2[k], wb1 = base2[64 + k];
    float ws0[8], ws1[8];
#pragma unroll
    for (int j = 0; j < 8; j++) { ws0[j] = sw2[k * 8 + j]; ws1[j] = sw2[512 + k * 8 + j]; }
    const int isbf = *flag;

    for (int n = wid; n < kNE; n += nw) {
        float x = h[(size_t)n * 64 + k];
        float sil = x / (1.f + __expf(-x));
        float b[8];
        bases8(x, t, r1, r2, r3, b);
        float o0 = sil * wb0, o1 = sil * wb1;
#pragma unroll
        for (int j = 0; j < 8; j++) {
            o0 = fmaf(b[j], ws0[j], o0);
            o1 = fmaf(b[j], ws1[j], o1);
        }
#pragma unroll
        for (int off = 32; off > 0; off >>= 1) {
            o0 += __shfl_down(o0, off, 64);
            o1 += __shfl_down(o1, off, 64);
        }
        if (lane == 0) {
            if (isbf) {
                __hip_bfloat16* ob = (__hip_bfloat16*)out;
                ob[(size_t)n * 2] = __float2bfloat16(o0);
                ob[(size_t)n * 2 + 1] = __float2bfloat16(o1);
            } else {
                ((float2*)out)[n] = make_float2(o0, o1);
            }
        }
    }
}

// ---------------- launch ----------------
extern "C" void kernel_launch(void* const* d_in, const int* in_sizes, int n_in, void* d_out, int out_size,
                              void* d_ws, size_t ws_size, hipStream_t stream) {
    (void)in_sizes; (void)n_in; (void)out_size; (void)ws_size;
    float* wsf = (float*)d_ws;
    int* wsi = (int*)d_ws;
    unsigned short* fbase = (unsigned short*)(wsi + FR_BASE_I);

    zero_kernel<<<(kNE + kNU + 255) / 256, 256, 0, stream>>>(wsi + I_CNT_UE, kNE + kNU);
    detect_kernel<<<1, 64, 0, stream>>>((const unsigned int*)d_in[21], wsi + O_FLAG);

    // fp32 converts: biases + grids + kan2 base
    ConvJobs jobs;
    const int srcIdx[7] = {4, 7, 10, 13, 21, 22, 25};
    const long long dstOff[7] = {O_BEM, O_BL1, O_BEN, O_BL2, O_GRID1, O_BASE2, O_GRID2};
    const int cnts[7] = {128, 128, 128, 128, 1536, 128, 768};
    for (int t = 0; t < 7; t++) {
        jobs.src[t] = d_in[srcIdx[t]];
        jobs.off[t] = (int)dstOff[t];
        jobs.n[t] = cnts[t];
    }
    convert_jobs_kernel<<<8, 256, 0, stream>>>(jobs, wsf, wsi + O_FLAG);
    premult_kernel<<<4, 256, 0, stream>>>(d_in[23], d_in[24], wsf + O_SW2, 1024, wsi + O_FLAG);

    // pack lin weights into exact-bf16 B-frags (one verified-pattern launch per weight)
    pack_frag<128, 64><<<4, 256, 0, stream>>>(d_in[3], fbase + U_WEM, wsi + O_FLAG);
    pack_frag<128, 128><<<8, 256, 0, stream>>>(d_in[6], fbase + U_W1N, wsi + O_FLAG);
    pack_frag<128, 128><<<8, 256, 0, stream>>>(d_in[8], fbase + U_W1R, wsi + O_FLAG);
    pack_frag<128, 128><<<8, 256, 0, stream>>>(d_in[9], fbase + U_WEN, wsi + O_FLAG);
    pack_frag<128, 128><<<8, 256, 0, stream>>>(d_in[11], fbase + U_WER, wsi + O_FLAG);
    pack_frag<128, 128><<<8, 256, 0, stream>>>(d_in[12], fbase + U_W2N, wsi + O_FLAG);
    pack_frag<128, 128><<<8, 256, 0, stream>>>(d_in[14], fbase + U_W2R, wsi + O_FLAG);
    // kan1 packs (verified)
    frag_base1_kernel<<<4, 256, 0, stream>>>(d_in[18], fbase + U_BASE1, wsi + O_FLAG);
    frag_sw1_kernel<<<32, 256, 0, stream>>>(d_in[19], d_in[20], fbase + U_SW1H, fbase + U_SW1L, wsi + O_FLAG);

    const int* ei_ue = (const int*)d_in[1];
    const int* ei_eu = (const int*)d_in[2];
    const int egrid = (kE + 255) / 256;

    // CSR build
    hist_kernel<<<egrid, 256, 0, stream>>>(ei_ue + kE, wsi + I_CNT_UE, kE);
    hist_kernel<<<egrid, 256, 0, stream>>>(ei_eu + kE, wsi + I_CNT_EU, kE);
    scan1_kernel<<<196, 256, 0, stream>>>(wsi + I_CNT_UE, wsi + I_RO_UE, wsi + I_BSUM_UE, kNE);
    scan2_kernel<<<1, 256, 0, stream>>>(wsi + I_BSUM_UE, wsi + I_BOFF_UE, 196);
    scan3_kernel<<<512, 256, 0, stream>>>(wsi + I_RO_UE, wsi + I_CUR_UE, wsi + I_BOFF_UE, kNE);
    scan1_kernel<<<98, 256, 0, stream>>>(wsi + I_CNT_EU, wsi + I_RO_EU, wsi + I_BSUM_EU, kNU);
    scan2_kernel<<<1, 256, 0, stream>>>(wsi + I_BSUM_EU, wsi + I_BOFF_EU, 98);
    scan3_kernel<<<512, 256, 0, stream>>>(wsi + I_RO_EU, wsi + I_CUR_EU, wsi + I_BOFF_EU, kNU);
    fill_kernel<<<egrid, 256, 0, stream>>>(ei_ue, ei_ue + kE, wsi + I_CUR_UE, wsi + I_SRT_UE, kE);
    fill_kernel<<<egrid, 256, 0, stream>>>(ei_eu, ei_eu + kE, wsi + I_CUR_EU, wsi + I_SRT_EU, kE);

    // 1. xe = x_email @ w_email^T + b_email -> B0
    lin_mfma<64, true, false, false, false><<<3125, 256, 0, stream>>>(
        d_in[0], nullptr, fbase + U_WEM, nullptr, wsf + O_BEM, wsf + O_B0, kNE, wsi + O_FLAG);

    // 2. mean_ue1 -> B1;  3. e1 = relu(lin(B1)+lin(xe)) -> B1
    agg_kernel<true><<<kNE / 4, 256, 0, stream>>>(d_in[5], wsf + O_B1, wsi + I_RO_UE, wsi + I_CNT_UE,
                                                  wsi + I_SRT_UE, kNE, wsi + O_FLAG);
    lin_mfma<128, false, false, true, true><<<3125, 256, 0, stream>>>(
        wsf + O_B1, wsf + O_B0, fbase + U_W1N, fbase + U_W1R, wsf + O_BL1, wsf + O_B1, kNE, wsi + O_FLAG);

    // 4. mean_eu -> B2;  5. u1 = relu(lin(B2)+lin(emb)) -> B2.  B0 free.
    agg_kernel<false><<<kNU / 4, 256, 0, stream>>>(wsf + O_B0, wsf + O_B2, wsi + I_RO_EU, wsi + I_CNT_EU,
                                                   wsi + I_SRT_EU, kNU, wsi + O_FLAG);
    lin_mfma<128, false, true, true, true><<<1563, 256, 0, stream>>>(
        wsf + O_B2, d_in[5], fbase + U_WEN, fbase + U_WER, wsf + O_BEN, wsf + O_B2, kNU, wsi + O_FLAG);

    // 6. mean_ue2 -> B0;  7. e2 = relu(lin(B0)+lin(e1)) -> B0.  B1 free.
    agg_kernel<false><<<kNE / 4, 256, 0, stream>>>(wsf + O_B2, wsf + O_B0, wsi + I_RO_UE, wsi + I_CNT_UE,
                                                   wsi + I_SRT_UE, kNE, wsi + O_FLAG);
    lin_mfma<128, false, false, true, true><<<3125, 256, 0, stream>>>(
        wsf + O_B0, wsf + O_B1, fbase + U_W2N, fbase + U_W2R, wsf + O_BL2, wsf + O_B0, kNE, wsi + O_FLAG);

    // 8. h = kan1_mfma(e2) -> B1;  9. out = kan2(h)
    kan1_mfma<<<3125, 256, 0, stream>>>(wsf + O_B0, fbase + U_BASE1, fbase + U_SW1H, fbase + U_SW1L,
                                        wsf + O_GRID1, wsf + O_B1);
    kan2_kernel<<<2048, 256, 0, stream>>>(wsf + O_B1, wsf + O_BASE2, wsf + O_SW2, wsf + O_GRID2, d_out,
                                          wsi + O_FLAG);
}